// Round 2
// baseline (191.448 us; speedup 1.0000x reference)
//
#include <hip/hip_runtime.h>

// OverlappingEdgeProcessor: x (4,6,16,512,512) f32.
// out = x except 4-wide edge strips blended with the adjacent face's strip.
// Restructured for streaming speed:
//  - blockIdx.y = face f (wave-uniform -> scalar branches)
//  - grid-stride within a face is a multiple of PLANE (65536 float4), so each
//    thread's (h, w4) is invariant across its 16 iterations -> branch mode,
//    adjacent-load delta, and weights are resolved ONCE before the loop.
//  - interior threads run a pure unrolled copy loop (batched loads, max MLP).
//
// Verified edge table (from the R1-passing kernel):
//   f0: top<-F4 row h (t=h/3), bot<-F5 row h-508 (t=(3-i)/3), L<-F2 col127, R<-F3 col0
//   f1: L<-F3(+2FS) col127, R<-F2(+1FS) col0
//   f2: top<-F4(+2FS) row 508+h, bot<-F5(+3FS) row h, L<-F1(-1FS), R<-F0(-2FS)
//   f3: L<-F0(-3FS) col127, R<-F1(-2FS) col0
//   f4: top<-F0(-4FS) row h, bot<-F2(-2FS) row h-508
//   f5: top<-F0(-5FS) row 508+h, bot<-F2(-3FS) row h
// Precedence: row edges (h) override col edges (w) in corners.

constexpr int W4 = 128;          // 512 floats / 4
constexpr int PLANE = 512 * W4;  // float4 per (b,f,c) plane = 65536
constexpr int FS = 16 * PLANE;   // face stride (C=16 planes) = 1048576

__global__ __launch_bounds__(256) void edge_blend_kernel(
    const float4* __restrict__ in, float4* __restrict__ out) {
  const int f = blockIdx.y;  // 0..5, wave-uniform

  int dfT = 0, offT = 0, dfB = 0, offB = 0, dfL = 0, dfR = 0;
  bool hasRow = false, hasCol = false;
  switch (f) {
    case 0: hasRow = true; hasCol = true; dfT = 4;  offT = 0;   dfB = 5;  offB = 0;   dfL = 2;  dfR = 3;  break;
    case 1: hasCol = true; dfL = 2;  dfR = 1;  break;
    case 2: hasRow = true; hasCol = true; dfT = 2;  offT = 508; dfB = 3;  offB = 508; dfL = -1; dfR = -2; break;
    case 3: hasCol = true; dfL = -3; dfR = -2; break;
    case 4: hasRow = true; dfT = -4; offT = 0;   dfB = -2; offB = 0;   break;
    case 5: hasRow = true; dfT = -5; offT = 508; dfB = -3; offB = 508; break;
  }

  const int l = blockIdx.x * blockDim.x + threadIdx.x;  // [0, 262144)
  const int w4 = l & (W4 - 1);
  const int h = (l >> 7) & 511;
  const int p0 = l >> 16;  // starting c-plane 0..3 (step 4)

  // Resolve this thread's mode once (loop-invariant).
  const float inv3 = 1.0f / 3.0f;
  int delta = 0;
  float wx = 1.f, wy = 1.f, wz = 1.f, wv = 1.f;  // weight on own element
  bool blend = false;
  if (hasRow && h >= 508) {            // bottom row edge (highest precedence)
    int i = h - 508;
    delta = dfB * FS + (offB - 508) * W4;
    float t = (3 - i) * inv3;
    wx = wy = wz = wv = t;
    blend = true;
  } else if (hasRow && h < 4) {        // top row edge
    delta = dfT * FS + offT * W4;
    float t = h * inv3;
    wx = wy = wz = wv = t;
    blend = true;
  } else if (hasCol && w4 == 0) {      // left col edge: er weights {0,1/3,2/3,1}
    delta = dfL * FS + (W4 - 1);
    wx = 0.f; wy = inv3; wz = 2.f * inv3; wv = 1.f;
    blend = true;
  } else if (hasCol && w4 == W4 - 1) { // right col edge: er weights {1,2/3,1/3,0}
    delta = dfR * FS - (W4 - 1);
    wx = 1.f; wy = 2.f * inv3; wz = inv3; wv = 0.f;
    blend = true;
  }

  const int base = f * FS + p0 * PLANE + (h << 7) + w4;
  if (!blend) {
    // Pure streaming copy: 4 batched loads per group, 16 elems total.
    for (int b = 0; b < 4; ++b) {
      const int ib = base + b * (6 * FS);
#pragma unroll
      for (int cj = 0; cj < 4; ++cj) {
        const int i = ib + cj * (4 * PLANE);
        out[i] = in[i];
      }
    }
  } else {
    const float ux = 1.f - wx, uy = 1.f - wy, uz = 1.f - wz, uv = 1.f - wv;
    for (int b = 0; b < 4; ++b) {
      const int ib = base + b * (6 * FS);
#pragma unroll
      for (int cj = 0; cj < 4; ++cj) {
        const int i = ib + cj * (4 * PLANE);
        const float4 er = in[i];
        const float4 ar = in[i + delta];
        out[i] = float4{er.x * wx + ar.x * ux, er.y * wy + ar.y * uy,
                        er.z * wz + ar.z * uz, er.w * wv + ar.w * uv};
      }
    }
  }
}

extern "C" void kernel_launch(void* const* d_in, const int* in_sizes, int n_in,
                              void* d_out, int out_size, void* d_ws,
                              size_t ws_size, hipStream_t stream) {
  const float4* in = (const float4*)d_in[0];
  float4* out = (float4*)d_out;
  // 262144 threads per face (1024 blocks x 256), 16 float4 each, 6 faces.
  hipLaunchKernelGGL(edge_blend_kernel, dim3(1024, 6), dim3(256), 0, stream,
                     in, out);
}

// Round 3
// 189.123 us; speedup vs baseline: 1.0123x; 1.0123x over previous
//
#include <hip/hip_runtime.h>

// OverlappingEdgeProcessor: x (4,6,16,512,512) f32.
// Strategy: bulk hipMemcpyAsync (out = in, 403 MB) + tiny edge kernel that
// overwrites only the 4-wide blend strips (~0.5% of elements).
//
// Edge tables (verified by the R1-passing kernel), delta = ar_idx - er_idx
// in float4 units. FS = face stride, W4 = 128 float4 per row.
// Col strips (faces 0-3, w4=0 'L' / w4=127 'R'), er weights per lane-elem:
//   L: {0,1/3,2/3,1}   R: {1,2/3,1/3,0}
//   f0: L +2FS+127, R +3FS-127 | f1: L +2FS+127, R +1FS-127
//   f2: L -1FS+127, R -2FS-127 | f3: L -3FS+127, R -2FS-127
// Row strips (faces 0,2,4,5; top h=i / bottom h=508+i), uniform weight
//   t = i/3 (top) or (3-i)/3 (bottom) on er:
//   f0: T +4FS,           B +5FS-508*W4
//   f2: T +2FS+508*W4,    B +3FS
//   f4: T -4FS,           B -2FS-508*W4
//   f5: T -5FS+508*W4,    B -3FS
// Precedence: row blends win in corners -> col threads on faces 0,2 skip
// h in [0,4) u [508,512) (the row thread writes those locations).

constexpr int W4 = 128;          // 512 floats / 4
constexpr int PLANE = 512 * W4;  // float4 per (b,f,c) plane = 65536
constexpr int FS = 16 * PLANE;   // face stride = 1048576 float4
constexpr int RO = 508 * W4;     // 508-row offset

__constant__ int kColDelta[4][2] = {
    {2 * FS + 127, 3 * FS - 127},
    {2 * FS + 127, 1 * FS - 127},
    {-1 * FS + 127, -2 * FS - 127},
    {-3 * FS + 127, -2 * FS - 127}};
__constant__ int kRowDelta[4][2] = {
    {4 * FS, 5 * FS - RO},
    {2 * FS + RO, 3 * FS},
    {-4 * FS, -2 * FS - RO},
    {-5 * FS + RO, -3 * FS}};
__constant__ int kRowFace[4] = {0, 2, 4, 5};

__global__ __launch_bounds__(256) void edge_fix_kernel(
    const float4* __restrict__ in, float4* __restrict__ out) {
  const int id = blockIdx.x * blockDim.x + threadIdx.x;  // [0, 524288)
  const float inv3 = 1.0f / 3.0f;

  if (id < 262144) {
    // ---- column strips ----
    int cid = id;
    int h = cid & 511; cid >>= 9;
    int c = cid & 15;  cid >>= 4;
    int s = cid & 1;   cid >>= 1;
    int face = cid & 3;           // faces 0..3
    int b = cid >> 2;
    if ((face == 0 || face == 2) && (h < 4 || h >= 508)) return;  // row wins
    int idx = (b * 6 + face) * FS + c * PLANE + h * W4 + (s ? 127 : 0);
    float4 er = in[idx];
    float4 ar = in[idx + kColDelta[face][s]];
    float4 r;
    if (s == 0) {  // left: er w = {0,1/3,2/3,1}
      r = float4{ar.x, er.y * inv3 + ar.y * (2.f * inv3),
                 er.z * (2.f * inv3) + ar.z * inv3, er.w};
    } else {       // right: er w = {1,2/3,1/3,0}
      r = float4{er.x, er.y * (2.f * inv3) + ar.y * inv3,
                 er.z * inv3 + ar.z * (2.f * inv3), ar.w};
    }
    out[idx] = r;
  } else {
    // ---- row strips ----
    int rid = id - 262144;
    int w4 = rid & 127; rid >>= 7;
    int i = rid & 3;    rid >>= 2;
    int c = rid & 15;   rid >>= 4;
    int s = rid & 1;    rid >>= 1;
    int fr = rid & 3;
    int b = rid >> 2;
    int face = kRowFace[fr];
    int h = s ? 508 + i : i;
    int idx = (b * 6 + face) * FS + c * PLANE + h * W4 + w4;
    float t = (s ? (3 - i) : i) * inv3;
    float u = 1.0f - t;
    float4 er = in[idx];
    float4 ar = in[idx + kRowDelta[fr][s]];
    out[idx] = float4{er.x * t + ar.x * u, er.y * t + ar.y * u,
                      er.z * t + ar.z * u, er.w * t + ar.w * u};
  }
}

extern "C" void kernel_launch(void* const* d_in, const int* in_sizes, int n_in,
                              void* d_out, int out_size, void* d_ws,
                              size_t ws_size, hipStream_t stream) {
  const float* in = (const float*)d_in[0];
  float* out = (float*)d_out;
  size_t bytes = (size_t)in_sizes[0] * sizeof(float);  // 402.7 MB
  // Bulk: out = in via the runtime's tuned D2D copy path.
  hipMemcpyAsync(out, in, bytes, hipMemcpyDeviceToDevice, stream);
  // Then overwrite the blend strips (524288 float4 items).
  hipLaunchKernelGGL(edge_fix_kernel, dim3(524288 / 256), dim3(256), 0,
                     stream, (const float4*)in, (float4*)out);
}